// Round 16
// baseline (96.015 us; speedup 1.0000x reference)
//
#include <hip/hip_runtime.h>
#include <hip/hip_bf16.h>

#define B_   8
#define N_   10000
#define H_   128
#define DIN_ 256
#define E_   160000
#define CAP_ 48                    // fixed CSR bucket capacity (P(overflow) ~ 4e-7, guarded)
// workspace bytes to zero: out_deg, cursor, fixed-capacity CSR
#define ZBYTES_ (2 * N_ * 4 + CAP_ * N_ * 8)

typedef unsigned int uint_;
typedef unsigned short ushort_;
typedef __attribute__((ext_vector_type(8))) short short8;
typedef __attribute__((ext_vector_type(4))) float f32x4;

__device__ __forceinline__ float sigmoidf_(float v) { return 1.f / (1.f + __expf(-v)); }
// tanh via exp, safe at +/-inf
__device__ __forceinline__ float tanh_fast(float v) { float e = __expf(2.f * v); return 1.f - 2.f / (e + 1.f); }

__device__ __forceinline__ ushort_ f2bf(float f) {
    union { float f; uint_ u; } v; v.f = f;
    uint_ r = v.u + 0x7fff + ((v.u >> 16) & 1);   // round-to-nearest-even
    return (ushort_)(r >> 16);
}
#define BF_LO(u) __uint_as_float((u) << 16)
#define BF_HI(u) __uint_as_float((u) & 0xffff0000u)

// ---- workspace zeroing (runtime fillBufferAligned uses a tiny grid) -----
__global__ __launch_bounds__(256) void zero_k(uint4* __restrict__ p) {
    int i = blockIdx.x * 256 + threadIdx.x;
    if (i < ZBYTES_ / 16) p[i] = (uint4){0u, 0u, 0u, 0u};
}

// ---- fused x-projections + W^T cast + out-degree count ------------------
// 1D grid, 657 blocks: bid<32 -> xproj (g=bid&3, b=bid>>2; g==3 = wt
// transpose); bid>=32 -> out-degree counting (in-degree now comes from the
// fill cursor itself -- scan-free fixed-capacity CSR needs no in_deg pass).
__global__ __launch_bounds__(256) void xdeg_k(const float* __restrict__ x,
                                              const float* __restrict__ w_r, const float* __restrict__ b_r,
                                              const float* __restrict__ w_z, const float* __restrict__ b_z,
                                              const float* __restrict__ w_h, const float* __restrict__ b_h,
                                              const float* __restrict__ gcn_w, ushort_* __restrict__ wt,
                                              float* __restrict__ xr, float* __restrict__ xz, float* __restrict__ xh,
                                              const int* __restrict__ src,
                                              int* __restrict__ out_deg) {
    __shared__ float part[2][128];
    const int bid = blockIdx.x;
    if (bid >= 32) {                 // out-degrees
        int e = (bid - 32) * 256 + threadIdx.x;
        if (e < E_) atomicAdd(&out_deg[src[e]], 1);
        return;
    }
    const int g = bid & 3, b = bid >> 2;
    if (g == 3) {                    // transpose + cast gcn_w (k,n) -> WT (n,k) bf16
        if (b != 0) return;
        const int t = threadIdx.x;
        const int n = t >> 1;
        const int kb = (t & 1) * 64;
        #pragma unroll
        for (int i = 0; i < 8; ++i) {
            int k = kb + i * 8;
            uint4 o;
            o.x = (uint_)f2bf(gcn_w[(k + 0) * H_ + n]) | ((uint_)f2bf(gcn_w[(k + 1) * H_ + n]) << 16);
            o.y = (uint_)f2bf(gcn_w[(k + 2) * H_ + n]) | ((uint_)f2bf(gcn_w[(k + 3) * H_ + n]) << 16);
            o.z = (uint_)f2bf(gcn_w[(k + 4) * H_ + n]) | ((uint_)f2bf(gcn_w[(k + 5) * H_ + n]) << 16);
            o.w = (uint_)f2bf(gcn_w[(k + 6) * H_ + n]) | ((uint_)f2bf(gcn_w[(k + 7) * H_ + n]) << 16);
            *(uint4*)(wt + n * H_ + k) = o;
        }
        return;
    }
    const float* __restrict__ w  = g == 0 ? w_r : (g == 1 ? w_z : w_h);
    const float* __restrict__ bs = g == 0 ? b_r : (g == 1 ? b_z : b_h);
    float* __restrict__ o        = g == 0 ? xr  : (g == 1 ? xz  : xh);
    const int k = threadIdx.x & 127, half = threadIdx.x >> 7;
    const float* xb = x + b * DIN_;
    float a = 0.f;
    #pragma unroll 8
    for (int d = half * 128; d < half * 128 + 128; ++d)
        a += xb[d] * w[d * H_ + k];
    part[half][k] = a;
    __syncthreads();
    if (half == 0) o[b * H_ + k] = a + part[1][k] + bs[k];
}

// raw A-tile loads (convert deferred to LDS-write time so the prefetch
// issues pure loads that fly under the previous tile's MFMA+epilogue)
__device__ __forceinline__ void load_tile_(f32x4 (&st)[8], const float* __restrict__ h,
                                           size_t bslab, int t, int tid) {
    #pragma unroll
    for (int i = 0; i < 8; ++i) {
        int f4 = i * 256 + tid;
        int row = f4 >> 5;
        int col4 = (f4 & 31) * 4;
        f32x4 v = {0.f, 0.f, 0.f, 0.f};
        int nn = t * 64 + row;
        if (nn < N_) v = *(const f32x4*)&h[(bslab + nn) * (size_t)H_ + col4];
        st[i] = v;
    }
}

// ---- fused CSR-fill + GEMM (hw = bf16(h_prev @ gcn_w)) ------------------
// bid < 632: gemm block (WT_s+A_s LDS-staged, batch-pinned b=bid&7 == XCD,
// 2 tiles/block, WT staged once, register prefetch of next A-tile; no
// scatter->readback barrier -- waves touch only their own 16 A_s rows).
// bid >= 632: SCAN-FREE CSR fill into fixed 48-entry buckets at n*CAP_
// (no offsets array); coef = rsqrt(out_deg[s]) computed inline; write
// guarded against (astronomically unlikely) bucket overflow. Fill hides
// under the gemm blocks' runtime.
__global__ __launch_bounds__(256) void fillgemm_k(const int* __restrict__ src, const int* __restrict__ dst,
                                                  int* __restrict__ cursor,
                                                  const int* __restrict__ out_deg, int2* __restrict__ csr_ed,
                                                  const float* __restrict__ h, const ushort_* __restrict__ wt,
                                                  ushort_* __restrict__ hw) {
    __shared__ ushort_ WT_s[H_ * H_];   // [n][k] bf16, swizzled: 32 KB
    __shared__ ushort_ A_s[64 * H_];    // [row][k] bf16, swizzled: 16 KB
    const int bid = blockIdx.x;
    const int tid = threadIdx.x;
    if (bid >= 632) {                   // ---- CSR fill (scan-free) ----
        int e = (bid - 632) * 256 + tid;
        if (e < E_) {
            int d = dst[e];
            int s = src[e];
            int pos = atomicAdd(&cursor[d], 1);
            if (pos < CAP_) {
                int od = out_deg[s];
                float coef = od > 0 ? rsqrtf((float)od) : 0.f;
                csr_ed[d * CAP_ + pos] = make_int2(s, __float_as_int(coef));
            }
        }
        return;
    }
    // ---- gemm ----
    const int b  = bid & 7;             // batch (0..7) == XCD
    const int ty = bid >> 3;            // 0..78
    const size_t bslab = (size_t)b * N_;

    // stage W^T once: 2048 16B-chunks; swizzle k-ushorts by ((n&7)<<3)
    #pragma unroll
    for (int i = 0; i < 8; ++i) {
        int c = i * 256 + tid;
        int n = c >> 4;
        int kus = (c & 15) * 8;
        uint4 v = ((const uint4*)wt)[c];
        *(uint4*)&WT_s[n * H_ + (kus ^ ((n & 7) << 3))] = v;
    }

    const int l = tid & 63;
    const int w = tid >> 6;
    const int lr = l & 15;
    const int kg = (l >> 4) * 8;
    const int arow = w * 16 + lr;

    int t = ty;
    f32x4 st[8];
    load_tile_(st, h, bslab, t, tid);   // prologue A-load (tile ty)

    for (;;) {
        // write staged regs -> A_s (cast here), swizzled
        #pragma unroll
        for (int i = 0; i < 8; ++i) {
            int f4 = i * 256 + tid;
            int row = f4 >> 5;
            int col4 = (f4 & 31) * 4;
            uint2 p;
            p.x = (uint_)f2bf(st[i][0]) | ((uint_)f2bf(st[i][1]) << 16);
            p.y = (uint_)f2bf(st[i][2]) | ((uint_)f2bf(st[i][3]) << 16);
            *(uint2*)&A_s[row * H_ + (col4 ^ ((row & 7) << 3))] = p;
        }
        __syncthreads();

        const int tn = t + 79;
        const bool more = tn < 157;
        f32x4 nx[8];
        if (more) load_tile_(nx, h, bslab, tn, tid);   // prefetch next tile

        f32x4 acc[8];
        #pragma unroll
        for (int nf = 0; nf < 8; ++nf) acc[nf] = (f32x4){0.f, 0.f, 0.f, 0.f};

        #pragma unroll
        for (int kk = 0; kk < 4; ++kk) {
            int kus = kk * 32 + kg;
            short8 av = *(const short8*)&A_s[arow * H_ + (kus ^ ((arow & 7) << 3))];
            #pragma unroll
            for (int nf = 0; nf < 8; ++nf) {
                int nrow = nf * 16 + lr;
                short8 bv = *(const short8*)&WT_s[nrow * H_ + (kus ^ ((nrow & 7) << 3))];
                acc[nf] = __builtin_amdgcn_mfma_f32_16x16x32_bf16(av, bv, acc[nf], 0, 0, 0);
            }
        }

        // epilogue: C/D layout col = lane&15, row = (lane>>4)*4 + r (m89).
        // Scatter + readback touch ONLY this wave's 16 A_s rows.
        const int n0 = t * 64;
        const int wrow0 = w * 16 + (l >> 4) * 4;
        #pragma unroll
        for (int nf = 0; nf < 8; ++nf) {
            int col = nf * 16 + lr;
            #pragma unroll
            for (int r = 0; r < 4; ++r) {
                int row = wrow0 + r;
                A_s[row * H_ + (col ^ ((row & 7) << 3))] = f2bf(acc[nf][r]);
            }
        }
        {
            int row = w * 16 + (l >> 2);      // own wave's rows only
            int c0 = (l & 3) * 32;            // 32 ushorts = 64B per lane
            int swz = (row & 7) << 3;
            if (n0 + row < N_) {
                uint4 o0 = *(const uint4*)&A_s[row * H_ + ((c0 +  0) ^ swz)];
                uint4 o1 = *(const uint4*)&A_s[row * H_ + ((c0 +  8) ^ swz)];
                uint4 o2 = *(const uint4*)&A_s[row * H_ + ((c0 + 16) ^ swz)];
                uint4 o3 = *(const uint4*)&A_s[row * H_ + ((c0 + 24) ^ swz)];
                uint4* dstp = (uint4*)(hw + (bslab + n0 + row) * (size_t)H_ + c0);
                dstp[0] = o0; dstp[1] = o1; dstp[2] = o2; dstp[3] = o3;
            }
        }
        if (!more) break;
        __syncthreads();   // all waves' readbacks done before A_s overwrite
        #pragma unroll
        for (int i = 0; i < 8; ++i) st[i] = nx[i];
        t = tn;
    }
}

// process 2 edges packed in one int4 (x,y)=edge0 (z,w)=edge1; 2-batch lanes
// Addresses stay WAVE-UNIFORM (SGPR base) -- r13 showed divergent gather
// addresses (cndmask'd src) cost +20% VALU and lose the saddr load form.
#define PROC2_(Q)                                                      \
    {                                                                  \
        int   s0_ = __builtin_amdgcn_readfirstlane((Q).x);             \
        float c0_ = __uint_as_float((uint_)(Q).y);                     \
        int   s1_ = __builtin_amdgcn_readfirstlane((Q).z);             \
        float c1_ = __uint_as_float((uint_)(Q).w);                     \
        uint2 u0_ = *(const uint2*)(hb + (size_t)s0_ * H_);            \
        uint2 u1_ = *(const uint2*)(hb + (size_t)s1_ * H_);            \
        a0 += c0_ * BF_LO(u0_.x); a1 += c0_ * BF_HI(u0_.x);            \
        a2 += c0_ * BF_LO(u0_.y); a3 += c0_ * BF_HI(u0_.y);            \
        a0 += c1_ * BF_LO(u1_.x); a1 += c1_ * BF_HI(u1_.x);            \
        a2 += c1_ * BF_LO(u1_.y); a3 += c1_ * BF_HI(u1_.y);            \
    }

// ---- aggregation of hw + fused GRU, TWO batches per wave ----------------
// Wave = one (node, batch-pair): lane = bsub*32 + cl; 4 cols/lane; gathers
// are dwordx2 (512B/instr). XCD pinning: pair = blockIdx.x & 3. Edge walk
// wave-uniform scalar (readfirstlane -> SGPR src).
// DEEP PROLOGUE (MSHR-bound fix): the fixed bucket guarantees entries past
// cursor[n] are ZERO (coef=0 -> no-op) and every bucket holds 24 int4s, so
// the wave UNCONDITIONALLY loads ed4[0..7] (16 edges) and issues all 16
// gathers back-to-back -- one exposed L2 latency covers the ENTIRE edge
// list for ~62% of nodes. Only dc>16 waves enter the residual loop.
__global__ __launch_bounds__(256) void agg_gru_k(const ushort_* __restrict__ hw,
                                                 const int* __restrict__ cursor,
                                                 const int2* __restrict__ csr_ed,
                                                 const float* __restrict__ gcn_b,
                                                 const float* __restrict__ xr, const float* __restrict__ xz,
                                                 const float* __restrict__ xh,
                                                 const float* __restrict__ h_prev, float* __restrict__ out) {
    const int lane = threadIdx.x & 63;
    const int wave = threadIdx.x >> 6;
    const int pr = blockIdx.x & 3;                  // batch pair (XCD-pinned)
    const int ng = blockIdx.x >> 2;                 // node group (0..2499)
    const int n  = ng * 4 + wave;
    const int bsub = lane >> 5;                     // batch within pair
    const int b  = pr * 2 + bsub;
    const int cl = lane & 31;                       // column quad (4 cols)
    const int col = cl * 4;
    int dc = __builtin_amdgcn_readfirstlane(cursor[n]);     // actual in-degree
    if (dc > CAP_) dc = CAP_;                               // overflow guard
    const int m = ((dc + 7) & ~7) >> 1;                     // int4 walk count
    const int4* __restrict__ ed4 = (const int4*)(csr_ed + n * CAP_);
    const ushort_* __restrict__ hb = hw + (size_t)b * (N_ * H_) + col;

    // deep prologue: 8 int4s = 16 edges, unconditional (zeros past dc)
    int4 q0 = ed4[0], q1 = ed4[1], q2 = ed4[2], q3 = ed4[3];
    int4 q4 = ed4[4], q5 = ed4[5], q6 = ed4[6], q7 = ed4[7];

    // hoisted epilogue operands (latency overlaps the gather walk)
    const float ni = dc > 0 ? rsqrtf((float)dc) : 0.f;
    const size_t off = ((size_t)b * N_ + n) * H_ + col;
    float4 hp = *(const float4*)(h_prev + off);
    float4 gb = *(const float4*)(gcn_b + col);
    float4 vr = *(const float4*)(xr + b * H_ + col);
    float4 vz = *(const float4*)(xz + b * H_ + col);
    float4 vh = *(const float4*)(xh + b * H_ + col);

    float a0 = 0.f, a1 = 0.f, a2 = 0.f, a3 = 0.f;
    PROC2_(q0); PROC2_(q1); PROC2_(q2); PROC2_(q3);
    PROC2_(q4); PROC2_(q5); PROC2_(q6); PROC2_(q7);
    // residual loop for dc > 16 (~38% of nodes), pads zero to x8
    for (int j = 8; j < m; j += 4) {
        int4 p0 = ed4[j + 0], p1 = ed4[j + 1], p2 = ed4[j + 2], p3 = ed4[j + 3];
        PROC2_(p0); PROC2_(p1); PROC2_(p2); PROC2_(p3);
    }

    float4 wv;
    {
        float hc = a0 * ni + gb.x;
        float rr = sigmoidf_(vr.x + hc);
        float zz = sigmoidf_(vz.x + hc);
        float ht = tanh_fast(vh.x + rr * hc);
        wv.x = (1.f - zz) * hp.x + zz * ht;
    }
    {
        float hc = a1 * ni + gb.y;
        float rr = sigmoidf_(vr.y + hc);
        float zz = sigmoidf_(vz.y + hc);
        float ht = tanh_fast(vh.y + rr * hc);
        wv.y = (1.f - zz) * hp.y + zz * ht;
    }
    {
        float hc = a2 * ni + gb.z;
        float rr = sigmoidf_(vr.z + hc);
        float zz = sigmoidf_(vz.z + hc);
        float ht = tanh_fast(vh.z + rr * hc);
        wv.z = (1.f - zz) * hp.z + zz * ht;
    }
    {
        float hc = a3 * ni + gb.w;
        float rr = sigmoidf_(vr.w + hc);
        float zz = sigmoidf_(vz.w + hc);
        float ht = tanh_fast(vh.w + rr * hc);
        wv.w = (1.f - zz) * hp.w + zz * ht;
    }
    *(float4*)(out + off) = wv;
}

extern "C" void kernel_launch(void* const* d_in, const int* in_sizes, int n_in,
                              void* d_out, int out_size, void* d_ws, size_t ws_size,
                              hipStream_t stream) {
    (void)in_sizes; (void)n_in; (void)out_size; (void)ws_size;
    const float* x      = (const float*)d_in[0];
    const float* h_prev = (const float*)d_in[1];
    const int*   src    = (const int*)d_in[2];
    const int*   dst    = (const int*)d_in[3];
    const float* w_r    = (const float*)d_in[4];
    const float* b_r    = (const float*)d_in[5];
    const float* w_z    = (const float*)d_in[6];
    const float* b_z    = (const float*)d_in[7];
    const float* w_h    = (const float*)d_in[8];
    const float* b_h    = (const float*)d_in[9];
    const float* gcn_w  = (const float*)d_in[10];
    const float* gcn_b  = (const float*)d_in[11];
    float* out = (float*)d_out;

    ushort_* hw = (ushort_*)d_ws;                  // B*N*H bf16 = 20.48 MB
    int* wsi = (int*)(hw + (size_t)B_ * N_ * H_);
    int* out_deg   = wsi;                          // N
    int* cursor    = wsi + N_;                     // N (in-degree counter)
    int2* csr_ed   = (int2*)(wsi + 2 * N_);        // CAP_*N fixed buckets (3.84 MB)
    float* xr = (float*)(csr_ed + CAP_ * N_);      // B*H
    float* xz = xr + B_ * H_;
    float* xh = xz + B_ * H_;
    ushort_* wt = (ushort_*)(xh + B_ * H_);        // H*H bf16 = 32 KB

    // zero out_deg, cursor, and the fixed-capacity CSR (pad: src=0, coef=0)
    zero_k<<<(ZBYTES_ / 16 + 255) / 256, 256, 0, stream>>>((uint4*)wsi);
    xdeg_k<<<32 + (E_ + 255) / 256, 256, 0, stream>>>(x, w_r, b_r, w_z, b_z, w_h, b_h,
                                                      gcn_w, wt, xr, xz, xh,
                                                      src, out_deg);
    fillgemm_k<<<632 + (E_ + 255) / 256, 256, 0, stream>>>(src, dst, cursor, out_deg, csr_ed,
                                                           h_prev, wt, hw);
    agg_gru_k<<<(N_ / 4) * 4, 256, 0, stream>>>(hw, cursor, csr_ed,
                                                gcn_b, xr, xz, xh, h_prev, out);
}

// Round 17
// 94.025 us; speedup vs baseline: 1.0212x; 1.0212x over previous
//
#include <hip/hip_runtime.h>
#include <hip/hip_bf16.h>

#define B_   8
#define N_   10000
#define H_   128
#define DIN_ 256
#define E_   160000
#define EPAD_ (E_ + 7 * N_ + 8)   // padded CSR capacity (each bucket rounded to x8)
// workspace bytes to zero: out_deg,in_deg,cursor + padded CSR
#define ZBYTES_ (3 * N_ * 4 + EPAD_ * 8)

typedef unsigned int uint_;
typedef unsigned short ushort_;
typedef __attribute__((ext_vector_type(8))) short short8;
typedef __attribute__((ext_vector_type(4))) float f32x4;

__device__ __forceinline__ float sigmoidf_(float v) { return 1.f / (1.f + __expf(-v)); }
// tanh via exp, safe at +/-inf
__device__ __forceinline__ float tanh_fast(float v) { float e = __expf(2.f * v); return 1.f - 2.f / (e + 1.f); }

__device__ __forceinline__ ushort_ f2bf(float f) {
    union { float f; uint_ u; } v; v.f = f;
    uint_ r = v.u + 0x7fff + ((v.u >> 16) & 1);   // round-to-nearest-even
    return (ushort_)(r >> 16);
}
#define BF_LO(u) __uint_as_float((u) << 16)
#define BF_HI(u) __uint_as_float((u) & 0xffff0000u)

// ---- workspace zeroing (runtime fillBufferAligned uses a tiny grid) -----
__global__ __launch_bounds__(256) void zero_k(uint4* __restrict__ p) {
    int i = blockIdx.x * 256 + threadIdx.x;
    if (i < ZBYTES_ / 16) p[i] = (uint4){0u, 0u, 0u, 0u};
}

// ---- norms + exclusive scan of PADDED in_deg -> CSR row offsets ---------
// Buckets padded to x8 so agg's edge walk needs no bounds logic (pad slots
// are zero-filled by zero_k: src=0, coef=0 -> FMA no-op).
__global__ __launch_bounds__(1024) void norms_scan_k(const int* __restrict__ out_deg, const int* __restrict__ in_deg,
                                                     float* __restrict__ norm_out, float* __restrict__ norm_in,
                                                     int* __restrict__ offsets) {
    __shared__ int buf[10240];       // 40 KB
    __shared__ int part[1024];
    const int tid = threadIdx.x;
    // phase A: coalesced load of in_deg into LDS (padded) + coalesced norm writes
    #pragma unroll
    for (int q = 0; q < 10; ++q) {
        int idx = q * 1024 + tid;
        int d = (idx < N_) ? in_deg[idx] : 0;
        buf[idx] = (idx < N_) ? ((d + 7) & ~7) : 0;
        if (idx < N_) {
            int od = out_deg[idx];
            norm_out[idx] = od > 0 ? rsqrtf((float)od) : 0.f;
            norm_in[idx]  = d  > 0 ? rsqrtf((float)d)  : 0.f;
        }
    }
    __syncthreads();
    // phase B: per-thread scan of its contiguous 10-chunk (from LDS)
    int local[10];
    int s = 0;
    #pragma unroll
    for (int q = 0; q < 10; ++q) {
        local[q] = s;
        s += buf[tid * 10 + q];
    }
    part[tid] = s;
    __syncthreads();
    // phase C: block scan of partials
    for (int off = 1; off < 1024; off <<= 1) {
        int v = (tid >= off) ? part[tid - off] : 0;
        __syncthreads();
        part[tid] += v;
        __syncthreads();
    }
    int pre = (tid > 0) ? part[tid - 1] : 0;
    // phase D: write results into LDS, then coalesced store
    #pragma unroll
    for (int q = 0; q < 10; ++q)
        buf[tid * 10 + q] = pre + local[q];
    __syncthreads();
    #pragma unroll
    for (int q = 0; q < 10; ++q) {
        int idx = q * 1024 + tid;
        if (idx < N_) offsets[idx] = buf[idx];
    }
    if (tid == 1023) offsets[N_] = part[1023];
}

// ---- fused x-projections + W^T cast + degree count ----------------------
// 1D grid, 657 blocks: bid<32 -> xproj (g=bid&3, b=bid>>2; g==3 = wt
// transpose); bid>=32 -> degree counting (625 blocks cover E).
__global__ __launch_bounds__(256) void xdeg_k(const float* __restrict__ x,
                                              const float* __restrict__ w_r, const float* __restrict__ b_r,
                                              const float* __restrict__ w_z, const float* __restrict__ b_z,
                                              const float* __restrict__ w_h, const float* __restrict__ b_h,
                                              const float* __restrict__ gcn_w, ushort_* __restrict__ wt,
                                              float* __restrict__ xr, float* __restrict__ xz, float* __restrict__ xh,
                                              const int* __restrict__ src, const int* __restrict__ dst,
                                              int* __restrict__ out_deg, int* __restrict__ in_deg) {
    __shared__ float part[2][128];
    const int bid = blockIdx.x;
    if (bid >= 32) {                 // degrees
        int e = (bid - 32) * 256 + threadIdx.x;
        if (e < E_) {
            atomicAdd(&out_deg[src[e]], 1);
            atomicAdd(&in_deg[dst[e]], 1);
        }
        return;
    }
    const int g = bid & 3, b = bid >> 2;
    if (g == 3) {                    // transpose + cast gcn_w (k,n) -> WT (n,k) bf16
        if (b != 0) return;
        const int t = threadIdx.x;
        const int n = t >> 1;
        const int kb = (t & 1) * 64;
        #pragma unroll
        for (int i = 0; i < 8; ++i) {
            int k = kb + i * 8;
            uint4 o;
            o.x = (uint_)f2bf(gcn_w[(k + 0) * H_ + n]) | ((uint_)f2bf(gcn_w[(k + 1) * H_ + n]) << 16);
            o.y = (uint_)f2bf(gcn_w[(k + 2) * H_ + n]) | ((uint_)f2bf(gcn_w[(k + 3) * H_ + n]) << 16);
            o.z = (uint_)f2bf(gcn_w[(k + 4) * H_ + n]) | ((uint_)f2bf(gcn_w[(k + 5) * H_ + n]) << 16);
            o.w = (uint_)f2bf(gcn_w[(k + 6) * H_ + n]) | ((uint_)f2bf(gcn_w[(k + 7) * H_ + n]) << 16);
            *(uint4*)(wt + n * H_ + k) = o;
        }
        return;
    }
    const float* __restrict__ w  = g == 0 ? w_r : (g == 1 ? w_z : w_h);
    const float* __restrict__ bs = g == 0 ? b_r : (g == 1 ? b_z : b_h);
    float* __restrict__ o        = g == 0 ? xr  : (g == 1 ? xz  : xh);
    const int k = threadIdx.x & 127, half = threadIdx.x >> 7;
    const float* xb = x + b * DIN_;
    float a = 0.f;
    #pragma unroll 8
    for (int d = half * 128; d < half * 128 + 128; ++d)
        a += xb[d] * w[d * H_ + k];
    part[half][k] = a;
    __syncthreads();
    if (half == 0) o[b * H_ + k] = a + part[1][k] + bs[k];
}

// raw A-tile loads (convert deferred to LDS-write time so the prefetch
// issues pure loads that fly under the previous tile's MFMA+epilogue)
__device__ __forceinline__ void load_tile_(f32x4 (&st)[8], const float* __restrict__ h,
                                           size_t bslab, int t, int tid) {
    #pragma unroll
    for (int i = 0; i < 8; ++i) {
        int f4 = i * 256 + tid;
        int row = f4 >> 5;
        int col4 = (f4 & 31) * 4;
        f32x4 v = {0.f, 0.f, 0.f, 0.f};
        int nn = t * 64 + row;
        if (nn < N_) v = *(const f32x4*)&h[(bslab + nn) * (size_t)H_ + col4];
        st[i] = v;
    }
}

// ---- fused CSR-fill + GEMM (hw = bf16(h_prev @ gcn_w)) ------------------
// bid < 632: gemm block (WT_s+A_s LDS-staged, batch-pinned b=bid&7 == XCD,
// 2 tiles/block, WT staged once) + register prefetch of the next A-tile;
// no scatter->readback barrier (waves touch only their own 16 A_s rows).
// bid >= 632: CSR bucket-fill (625 blocks), hides under gemm runtime.
__global__ __launch_bounds__(256) void fillgemm_k(const int* __restrict__ src, const int* __restrict__ dst,
                                                  const int* __restrict__ offsets, int* __restrict__ cursor,
                                                  const float* __restrict__ norm_out, int2* __restrict__ csr_ed,
                                                  const float* __restrict__ h, const ushort_* __restrict__ wt,
                                                  ushort_* __restrict__ hw) {
    __shared__ ushort_ WT_s[H_ * H_];   // [n][k] bf16, swizzled: 32 KB
    __shared__ ushort_ A_s[64 * H_];    // [row][k] bf16, swizzled: 16 KB
    const int bid = blockIdx.x;
    const int tid = threadIdx.x;
    if (bid >= 632) {                   // ---- CSR fill ----
        int e = (bid - 632) * 256 + tid;
        if (e < E_) {
            int d = dst[e];
            int s = src[e];
            int pos = offsets[d] + atomicAdd(&cursor[d], 1);
            csr_ed[pos] = make_int2(s, __float_as_int(norm_out[s]));
        }
        return;
    }
    // ---- gemm ----
    const int b  = bid & 7;             // batch (0..7) == XCD
    const int ty = bid >> 3;            // 0..78
    const size_t bslab = (size_t)b * N_;

    // stage W^T once: 2048 16B-chunks; swizzle k-ushorts by ((n&7)<<3)
    #pragma unroll
    for (int i = 0; i < 8; ++i) {
        int c = i * 256 + tid;
        int n = c >> 4;
        int kus = (c & 15) * 8;
        uint4 v = ((const uint4*)wt)[c];
        *(uint4*)&WT_s[n * H_ + (kus ^ ((n & 7) << 3))] = v;
    }

    const int l = tid & 63;
    const int w = tid >> 6;
    const int lr = l & 15;
    const int kg = (l >> 4) * 8;
    const int arow = w * 16 + lr;

    int t = ty;
    f32x4 st[8];
    load_tile_(st, h, bslab, t, tid);   // prologue A-load (tile ty)

    for (;;) {
        // write staged regs -> A_s (cast here), swizzled
        #pragma unroll
        for (int i = 0; i < 8; ++i) {
            int f4 = i * 256 + tid;
            int row = f4 >> 5;
            int col4 = (f4 & 31) * 4;
            uint2 p;
            p.x = (uint_)f2bf(st[i][0]) | ((uint_)f2bf(st[i][1]) << 16);
            p.y = (uint_)f2bf(st[i][2]) | ((uint_)f2bf(st[i][3]) << 16);
            *(uint2*)&A_s[row * H_ + (col4 ^ ((row & 7) << 3))] = p;
        }
        __syncthreads();

        const int tn = t + 79;
        const bool more = tn < 157;
        f32x4 nx[8];
        if (more) load_tile_(nx, h, bslab, tn, tid);   // prefetch next tile

        f32x4 acc[8];
        #pragma unroll
        for (int nf = 0; nf < 8; ++nf) acc[nf] = (f32x4){0.f, 0.f, 0.f, 0.f};

        #pragma unroll
        for (int kk = 0; kk < 4; ++kk) {
            int kus = kk * 32 + kg;
            short8 av = *(const short8*)&A_s[arow * H_ + (kus ^ ((arow & 7) << 3))];
            #pragma unroll
            for (int nf = 0; nf < 8; ++nf) {
                int nrow = nf * 16 + lr;
                short8 bv = *(const short8*)&WT_s[nrow * H_ + (kus ^ ((nrow & 7) << 3))];
                acc[nf] = __builtin_amdgcn_mfma_f32_16x16x32_bf16(av, bv, acc[nf], 0, 0, 0);
            }
        }

        // epilogue: C/D layout col = lane&15, row = (lane>>4)*4 + r (m89).
        // Scatter + readback touch ONLY this wave's 16 A_s rows.
        const int n0 = t * 64;
        const int wrow0 = w * 16 + (l >> 4) * 4;
        #pragma unroll
        for (int nf = 0; nf < 8; ++nf) {
            int col = nf * 16 + lr;
            #pragma unroll
            for (int r = 0; r < 4; ++r) {
                int row = wrow0 + r;
                A_s[row * H_ + (col ^ ((row & 7) << 3))] = f2bf(acc[nf][r]);
            }
        }
        {
            int row = w * 16 + (l >> 2);      // own wave's rows only
            int c0 = (l & 3) * 32;            // 32 ushorts = 64B per lane
            int swz = (row & 7) << 3;
            if (n0 + row < N_) {
                uint4 o0 = *(const uint4*)&A_s[row * H_ + ((c0 +  0) ^ swz)];
                uint4 o1 = *(const uint4*)&A_s[row * H_ + ((c0 +  8) ^ swz)];
                uint4 o2 = *(const uint4*)&A_s[row * H_ + ((c0 + 16) ^ swz)];
                uint4 o3 = *(const uint4*)&A_s[row * H_ + ((c0 + 24) ^ swz)];
                uint4* dstp = (uint4*)(hw + (bslab + n0 + row) * (size_t)H_ + c0);
                dstp[0] = o0; dstp[1] = o1; dstp[2] = o2; dstp[3] = o3;
            }
        }
        if (!more) break;
        __syncthreads();   // all waves' readbacks done before A_s overwrite
        #pragma unroll
        for (int i = 0; i < 8; ++i) st[i] = nx[i];
        t = tn;
    }
}

// process 2 edges packed in one int4 (x,y)=edge0 (z,w)=edge1; 2-batch lanes
// Addresses stay WAVE-UNIFORM (SGPR base) -- r13 showed divergent gather
// addresses (cndmask'd src) cost +20% VALU and lose the saddr load form.
#define PROC2_(Q)                                                      \
    {                                                                  \
        int   s0_ = __builtin_amdgcn_readfirstlane((Q).x);             \
        float c0_ = __uint_as_float((uint_)(Q).y);                     \
        int   s1_ = __builtin_amdgcn_readfirstlane((Q).z);             \
        float c1_ = __uint_as_float((uint_)(Q).w);                     \
        uint2 u0_ = *(const uint2*)(hb + (size_t)s0_ * H_);            \
        uint2 u1_ = *(const uint2*)(hb + (size_t)s1_ * H_);            \
        a0 += c0_ * BF_LO(u0_.x); a1 += c0_ * BF_HI(u0_.x);            \
        a2 += c0_ * BF_LO(u0_.y); a3 += c0_ * BF_HI(u0_.y);            \
        a0 += c1_ * BF_LO(u1_.x); a1 += c1_ * BF_HI(u1_.x);            \
        a2 += c1_ * BF_LO(u1_.y); a3 += c1_ * BF_HI(u1_.y);            \
    }

// ---- aggregation of hw + fused GRU, TWO batches per wave (r12 best) -----
// Wave = one (node, batch-pair): lane = bsub*32 + cl; 4 cols/lane; gathers
// are dwordx2 (512B/instr). XCD pinning: pair = blockIdx.x & 3. Edge walk
// wave-uniform scalar (readfirstlane -> SGPR src); CSR buckets padded to
// x8 -> no bounds logic; entries as int4, 1 group prefetched ahead.
__global__ __launch_bounds__(256) void agg_gru_k(const ushort_* __restrict__ hw, const int* __restrict__ offsets,
                                                 const float* __restrict__ norm_in,
                                                 const int2* __restrict__ csr_ed,
                                                 const float* __restrict__ gcn_b,
                                                 const float* __restrict__ xr, const float* __restrict__ xz,
                                                 const float* __restrict__ xh,
                                                 const float* __restrict__ h_prev, float* __restrict__ out) {
    const int lane = threadIdx.x & 63;
    const int wave = threadIdx.x >> 6;
    const int pr = blockIdx.x & 3;                  // batch pair (XCD-pinned)
    const int ng = blockIdx.x >> 2;                 // node group (0..2499)
    const int n  = ng * 4 + wave;
    const int bsub = lane >> 5;                     // batch within pair
    const int b  = pr * 2 + bsub;
    const int cl = lane & 31;                       // column quad (4 cols)
    const int col = cl * 4;
    const int o  = __builtin_amdgcn_readfirstlane(offsets[n]);
    const int dc = __builtin_amdgcn_readfirstlane(offsets[n + 1]) - o;   // multiple of 8
    const int4* __restrict__ ed4 = (const int4*)(csr_ed + o);            // 16B aligned (o even)
    const ushort_* __restrict__ hb = hw + (size_t)b * (N_ * H_) + col;   // per-lane voffset const

    // hoisted epilogue operands (latency overlaps the gather walk)
    const float ni = norm_in[n];
    const size_t off = ((size_t)b * N_ + n) * H_ + col;
    float4 hp = *(const float4*)(h_prev + off);
    float4 gb = *(const float4*)(gcn_b + col);
    float4 vr = *(const float4*)(xr + b * H_ + col);
    float4 vz = *(const float4*)(xz + b * H_ + col);
    float4 vh = *(const float4*)(xh + b * H_ + col);

    float a0 = 0.f, a1 = 0.f, a2 = 0.f, a3 = 0.f;
    if (dc > 0) {
        const int m = dc >> 1;                       // int4 count, multiple of 4
        int4 q0 = ed4[0], q1 = ed4[1], q2 = ed4[2], q3 = ed4[3];
        for (int j = 4; j < m; j += 4) {
            int4 p0 = ed4[j + 0], p1 = ed4[j + 1], p2 = ed4[j + 2], p3 = ed4[j + 3];
            PROC2_(q0); PROC2_(q1); PROC2_(q2); PROC2_(q3);
            q0 = p0; q1 = p1; q2 = p2; q3 = p3;
        }
        PROC2_(q0); PROC2_(q1); PROC2_(q2); PROC2_(q3);
    }

    float4 wv;
    {
        float hc = a0 * ni + gb.x;
        float rr = sigmoidf_(vr.x + hc);
        float zz = sigmoidf_(vz.x + hc);
        float ht = tanh_fast(vh.x + rr * hc);
        wv.x = (1.f - zz) * hp.x + zz * ht;
    }
    {
        float hc = a1 * ni + gb.y;
        float rr = sigmoidf_(vr.y + hc);
        float zz = sigmoidf_(vz.y + hc);
        float ht = tanh_fast(vh.y + rr * hc);
        wv.y = (1.f - zz) * hp.y + zz * ht;
    }
    {
        float hc = a2 * ni + gb.z;
        float rr = sigmoidf_(vr.z + hc);
        float zz = sigmoidf_(vz.z + hc);
        float ht = tanh_fast(vh.z + rr * hc);
        wv.z = (1.f - zz) * hp.z + zz * ht;
    }
    {
        float hc = a3 * ni + gb.w;
        float rr = sigmoidf_(vr.w + hc);
        float zz = sigmoidf_(vz.w + hc);
        float ht = tanh_fast(vh.w + rr * hc);
        wv.w = (1.f - zz) * hp.w + zz * ht;
    }
    *(float4*)(out + off) = wv;
}

extern "C" void kernel_launch(void* const* d_in, const int* in_sizes, int n_in,
                              void* d_out, int out_size, void* d_ws, size_t ws_size,
                              hipStream_t stream) {
    (void)in_sizes; (void)n_in; (void)out_size; (void)ws_size;
    const float* x      = (const float*)d_in[0];
    const float* h_prev = (const float*)d_in[1];
    const int*   src    = (const int*)d_in[2];
    const int*   dst    = (const int*)d_in[3];
    const float* w_r    = (const float*)d_in[4];
    const float* b_r    = (const float*)d_in[5];
    const float* w_z    = (const float*)d_in[6];
    const float* b_z    = (const float*)d_in[7];
    const float* w_h    = (const float*)d_in[8];
    const float* b_h    = (const float*)d_in[9];
    const float* gcn_w  = (const float*)d_in[10];
    const float* gcn_b  = (const float*)d_in[11];
    float* out = (float*)d_out;

    ushort_* hw = (ushort_*)d_ws;                  // B*N*H bf16 = 20.48 MB
    int* wsi = (int*)(hw + (size_t)B_ * N_ * H_);
    int* out_deg   = wsi;                          // N
    int* in_deg    = wsi + N_;                     // N
    int* cursor    = wsi + 2 * N_;                 // N
    int2* csr_ed   = (int2*)(wsi + 3 * N_);        // EPAD_ packed (src, coef)
    int* offsets   = (int*)(csr_ed + EPAD_);       // N+1
    float* norm_out = (float*)(offsets + N_ + 1);  // N
    float* norm_in  = norm_out + N_;               // N
    float* xr = norm_in + N_;                      // B*H
    float* xz = xr + B_ * H_;
    float* xh = xz + B_ * H_;
    ushort_* wt = (ushort_*)(xh + B_ * H_);        // H*H bf16 = 32 KB

    // zero out_deg, in_deg, cursor AND the padded CSR (pad slots: src=0, coef=0)
    zero_k<<<(ZBYTES_ / 16 + 255) / 256, 256, 0, stream>>>((uint4*)wsi);
    xdeg_k<<<32 + (E_ + 255) / 256, 256, 0, stream>>>(x, w_r, b_r, w_z, b_z, w_h, b_h,
                                                      gcn_w, wt, xr, xz, xh,
                                                      src, dst, out_deg, in_deg);
    norms_scan_k<<<1, 1024, 0, stream>>>(out_deg, in_deg, norm_out, norm_in, offsets);
    fillgemm_k<<<632 + (E_ + 255) / 256, 256, 0, stream>>>(src, dst, offsets, cursor, norm_out, csr_ed,
                                                           h_prev, wt, hw);
    agg_gru_k<<<(N_ / 4) * 4, 256, 0, stream>>>(hw, offsets, norm_in, csr_ed,
                                                gcn_b, xr, xz, xh, h_prev, out);
}